// Round 21
// baseline (1238.509 us; speedup 1.0000x reference)
//
#include <hip/hip_runtime.h>
#include <stdint.h>

#define HW 256
#define HWP 258
#define CH 32
#define CVN 64
#define NPIX (HW*HW)
#define KK 8
#define CSTRT (HWP*HWP)

// PRNG (verified r3): partitionable threefry + SPLIT-key randint.
// r20 post-mortem: split-eval VGPR win wasted — 512 blocks = 2/CU block-cap.
// r21: 16x8-px tiles everywhere; eval LDS = 23KB q-tile only -> 4 blocks/CU
//   x 4 waves = 16 waves/CU, 1024 blocks ALL co-resident -> 4-band 64-row
//   lockstep + batch-split XCD remap. Init shares gen->eval->merge (256
//   entries/band = full lanes). Scratch in vp region; vtr after iter loop.

// ---------------- Threefry-2x32 (JAX-compatible) ----------------
__host__ __device__ __forceinline__ void tf2x32(uint32_t k0, uint32_t k1,
                                                uint32_t x0, uint32_t x1,
                                                uint32_t &o0, uint32_t &o1) {
  const uint32_t ks2 = k0 ^ k1 ^ 0x1BD11BDAu;
  x0 += k0; x1 += k1;
#define TFR(r) x0 += x1; x1 = (x1 << (r)) | (x1 >> (32 - (r))); x1 ^= x0;
  TFR(13) TFR(15) TFR(26) TFR(6)
  x0 += k1;  x1 += ks2 + 1u;
  TFR(17) TFR(29) TFR(16) TFR(24)
  x0 += ks2; x1 += k0 + 2u;
  TFR(13) TFR(15) TFR(26) TFR(6)
  x0 += k0;  x1 += k1 + 3u;
  TFR(17) TFR(29) TFR(16) TFR(24)
  x0 += k1;  x1 += ks2 + 4u;
  TFR(13) TFR(15) TFR(26) TFR(6)
  x0 += ks2; x1 += k0 + 5u;
#undef TFR
  o0 = x0; o1 = x1;
}

__device__ __forceinline__ uint32_t tfbits(uint32_t k0, uint32_t k1, uint32_t idx) {
  uint32_t a, b;
  tf2x32(k0, k1, 0u, idx, a, b);
  return a ^ b;
}

// batch-split remap: XCD (bid%8) 0-3 -> batch 0, 4-7 -> batch 1; tin 0..511
__device__ __forceinline__ void remap1024(int bid, int &b, int &tin) {
  b = ((bid & 7) >= 4) ? 1 : 0;
  tin = ((bid >> 3) << 2) | (bid & 3);
}

// ------- tiled transpose+pad: (C=32, 65536) -> padded (258,258,32) -------
__global__ __launch_bounds__(256) void tpad_k(const float* __restrict__ src,
                                              float* __restrict__ dst) {
  __shared__ float tile[CH][65];
  int t = blockIdx.x;
  int b = t >> 10;
  int p0 = (t & 1023) * 64;
  int tid = threadIdx.x;
  const float* sb = src + (size_t)b * CH * NPIX;
#pragma unroll
  for (int i = 0; i < 8; i++) {
    int idx = i * 256 + tid;
    int c = idx >> 6, px = idx & 63;
    tile[c][px] = sb[c * NPIX + p0 + px];
  }
  __syncthreads();
  float* db = dst + (size_t)b * CSTRT * CH;
#pragma unroll
  for (int i = 0; i < 8; i++) {
    int idx = i * 256 + tid;
    int px = idx >> 5, c = idx & 31;
    int p = p0 + px;
    int y = p >> 8, x = p & 255;
    db[((size_t)(y + 1) * HWP + (x + 1)) * CH + c] = tile[c][px];
  }
}

// ------- tiled transpose: v (64, 65536) -> vp (65536, 64) -------
__global__ __launch_bounds__(256) void vtr_k(const float* __restrict__ v,
                                             float* __restrict__ vp) {
  __shared__ float tile[CVN][65];
  int t = blockIdx.x;
  int b = t >> 10;
  int p0 = (t & 1023) * 64;
  int tid = threadIdx.x;
  const float* sb = v + (size_t)b * CVN * NPIX;
#pragma unroll
  for (int i = 0; i < 16; i++) {
    int idx = i * 256 + tid;
    int c = idx >> 6, px = idx & 63;
    tile[c][px] = sb[c * NPIX + p0 + px];
  }
  __syncthreads();
  float* db = vp + (size_t)b * NPIX * CVN;
#pragma unroll
  for (int i = 0; i < 16; i++) {
    int idx = i * 256 + tid;
    int px = idx >> 6, c = idx & 63;
    db[(size_t)(p0 + px) * CVN + c] = tile[c][px];
  }
}

// ---- cost: tap-outer FULL unroll; per-tap ch-ascending; flat combine ----
// qt has 18-col stride; works for 18- or 10-row tiles.
__device__ __forceinline__ float cost_full(const float* __restrict__ qt,
                                           int py, int px,
                                           const float* __restrict__ kb2,
                                           int sy, int sx) {
#pragma clang fp contract(off)
  float S[3][3];
  const float* kb = kb2 + ((size_t)sy * HWP + sx) * CH;
#pragma unroll
  for (int dy = 0; dy < 3; dy++) {
#pragma unroll
    for (int dx = 0; dx < 3; dx++) {
      int row = py + dy, col = px + dx;
      const float* qrow = &qt[(row * 18 + col) * 32];
      int rot = 4 * ((row * 3 + col) & 7);
      const float* kr = kb + (dy * HWP + dx) * CH;
      float4 kv[8], qv[8];
#pragma unroll
      for (int i = 0; i < 8; i++) kv[i] = ((const float4*)kr)[i];
#pragma unroll
      for (int i = 0; i < 8; i++)
        qv[i] = *(const float4*)(&qrow[(i * 4 + rot) & 31]);
      float s = 0.f;
#pragma unroll
      for (int i = 0; i < 8; i++) {
        float d;
        d = qv[i].x - kv[i].x; s = s + d * d;
        d = qv[i].y - kv[i].y; s = s + d * d;
        d = qv[i].z - kv[i].z; s = s + d * d;
        d = qv[i].w - kv[i].w; s = s + d * d;
      }
      S[dy][dx] = s;
    }
  }
  float cost = 0.f;
#pragma unroll
  for (int dy = 0; dy < 3; dy++)
#pragma unroll
    for (int dx = 0; dx < 3; dx++) cost = cost + S[dy][dx];
  return cost;
}

// load q tile: padded rows ty..ty+9, cols tx..tx+17, rot-swizzled
__device__ __forceinline__ void load_qtile8(const float* __restrict__ qpb,
                                            float* __restrict__ qt,
                                            int ty, int tx, int tid) {
  for (int i = tid; i < 10 * 18 * 8; i += 256) {
    int c4 = i & 7;
    int col = (i >> 3) % 18;
    int row = (i >> 3) / 18;
    float4 v = *(const float4*)(qpb + ((size_t)(ty + row) * HWP + (tx + col)) * CH + c4 * 4);
    *(float4*)(&qt[(row * 18 + col) * 32 +
                   ((c4 * 4 + 4 * ((row * 3 + col) & 7)) & 31)]) = v;
  }
}

// ---------------- prop candidate helper (r3-verified) ----------------
__device__ __forceinline__ void prop_cand(const int* __restrict__ sI, int base,
                                          int y, int x, int c, int &nsy, int &nsx) {
  int np;
  if (c == 0)      np = (y << 8) | ((x + HW - 1) & (HW - 1));
  else if (c == 1) np = (y << 8) | ((x + 1) & (HW - 1));
  else if (c == 2) np = (((y + HW - 1) & (HW - 1)) << 8) | x;
  else             np = (((y + 1) & (HW - 1)) << 8) | x;
  int sv = sI[base + np];
  if (c == 0)      { nsy = sv >> 8;       nsx = (sv & 255) + 1; }
  else if (c == 1) { nsy = sv >> 8;       nsx = (sv & 255) - 1; }
  else if (c == 2) { nsy = (sv >> 8) + 1; nsx = sv & 255; }
  else             { nsy = (sv >> 8) - 1; nsx = sv & 255; }
}

__device__ __forceinline__ int rand_off(uint4 K, uint32_t p, int s) {
  uint32_t hi = tfbits(K.x, K.y, p), lo = tfbits(K.z, K.w, p);
  return (s == 0) ? (int)(((hi % 257u) + (lo % 257u)) % 257u) - 128
                  : (int)((((hi % 129u) * 16u) + (lo % 129u)) % 129u) - 64;
}

// ---- init gen: 8 PRNG cands/px, 4-band bin -> entG/bstG/scandG ----
__global__ __launch_bounds__(256) void igen_k(
    int* __restrict__ scandG, uint32_t* __restrict__ entG,
    int* __restrict__ bstG, uint4 ikA, uint4 ikB) {
  __shared__ uint32_t ent[1024];
  __shared__ int bcnt[4], bstart[5], boff[4];
  int tid = threadIdx.x;
  int b, tin;
  remap1024(blockIdx.x, b, tin);
  int ty = (tin >> 4) * 8, tx = (tin & 15) * 16;
  if (tid < 4) bcnt[tid] = 0;
  __syncthreads();
  uint4 K = b ? ikB : ikA;
  int pi = tid & 127;
  int p = ((ty + (pi >> 4)) << 8) | (tx + (pi & 15));
  int gp8 = (b * NPIX + p) * 8;
  uint32_t mye[4];
  int myb[4];
#pragma unroll
  for (int r = 0; r < 4; r++) {
    int j = (tid >> 7) + 2 * r;        // this thread's j's
    uint32_t cand = (uint32_t)(j * NPIX + p);
    int sy = (int)(tfbits(K.x, K.y, cand) & 255u);
    int sx = (int)(tfbits(K.z, K.w, cand) & 255u);
    int ps = (sy << 8) | sx;
    scandG[gp8 + j] = ps;
    mye[r] = ((uint32_t)ps << 11) | ((uint32_t)pi << 3) | (uint32_t)j;
    myb[r] = sy >> 6;
    atomicAdd(&bcnt[myb[r]], 1);
  }
  __syncthreads();
  if (tid == 0) {
    int s = 0;
#pragma unroll
    for (int i = 0; i < 4; i++) { bstart[i] = s; boff[i] = s; s += bcnt[i]; }
    bstart[4] = s;
  }
  __syncthreads();
#pragma unroll
  for (int r = 0; r < 4; r++) {
    int pos = atomicAdd(&boff[myb[r]], 1);
    ent[pos] = mye[r];
  }
  __syncthreads();
  int total = bstart[4];
  for (int i = tid; i < total; i += 256) entG[blockIdx.x * 1024 + i] = ent[i];
  if (tid < 5) bstG[blockIdx.x * 8 + tid] = bstart[tid];
}

// ---- iter gen: cands + dedup + 4-band bin -> entG/bstG/scandG/dupjG ----
__global__ __launch_bounds__(256) void ggen_k(
    const int* __restrict__ sI,
    int* __restrict__ scandG, int* __restrict__ dupjG,
    uint32_t* __restrict__ entG, int* __restrict__ bstG,
    uint4 A0y, uint4 A0x, uint4 A1y, uint4 A1x,
    uint4 B0y, uint4 B0x, uint4 B1y, uint4 B1x) {
  __shared__ uint32_t ent[768];
  __shared__ int pcurS[128][8];
  __shared__ int bcnt[4], bstart[5], boff[4];
  int tid = threadIdx.x;
  int b, tin;
  remap1024(blockIdx.x, b, tin);
  int ty = (tin >> 4) * 8, tx = (tin & 15) * 16;
  int base = b * KK * NPIX;
  if (tid < 4) bcnt[tid] = 0;
  // stage pcur (coalesced)
  for (int e = tid; e < 1024; e += 256) {
    int pi = e & 127, jj = e >> 7;
    pcurS[pi][jj] = sI[base + jj * NPIX + (((ty + (pi >> 4)) << 8) | (tx + (pi & 15)))];
  }
  __syncthreads();

  int pi = tid & 127;
  int y = ty + (pi >> 4), x = tx + (pi & 15);
  int p = (y << 8) | x;
  int gp8 = (b * NPIX + p) * 8;
  uint32_t mye[3];
  int myb[3];
  int valid[3];
#pragma unroll
  for (int r = 0; r < 3; r++) {
    int j = (tid >> 7) + 2 * r;        // j 0..5
    int nsy, nsx;
    if (j < 4) {
      prop_cand(sI, base, y, x, j, nsy, nsx);
    } else {
      int svc = pcurS[pi][0];
      int s = j - 4;
      uint4 KY = b ? (s ? B1y : B0y) : (s ? A1y : A0y);
      uint4 KX = b ? (s ? B1x : B0x) : (s ? A1x : A0x);
      nsy = (svc >> 8) + rand_off(KY, (uint32_t)p, s);
      nsx = (svc & 255) + rand_off(KX, (uint32_t)p, s);
    }
    nsy = min(max(nsy, 0), HW - 1);
    nsx = min(max(nsx, 0), HW - 1);
    int ps = (nsy << 8) | nsx;
    scandG[gp8 + j] = ps;
    int d = -1;
#pragma unroll
    for (int jj = 0; jj < KK; jj++)
      if (d < 0 && pcurS[pi][jj] == ps) d = jj;
    dupjG[gp8 + j] = d;
    valid[r] = (d < 0);
    if (d < 0) {
      mye[r] = ((uint32_t)ps << 11) | ((uint32_t)pi << 3) | (uint32_t)j;
      myb[r] = nsy >> 6;
      atomicAdd(&bcnt[myb[r]], 1);
    }
  }
  __syncthreads();
  if (tid == 0) {
    int s = 0;
#pragma unroll
    for (int i = 0; i < 4; i++) { bstart[i] = s; boff[i] = s; s += bcnt[i]; }
    bstart[4] = s;
  }
  __syncthreads();
#pragma unroll
  for (int r = 0; r < 3; r++) {
    if (valid[r]) {
      int pos = atomicAdd(&boff[myb[r]], 1);
      ent[pos] = mye[r];
    }
  }
  __syncthreads();
  int total = bstart[4];
  for (int i = tid; i < total; i += 256) entG[blockIdx.x * 1024 + i] = ent[i];
  if (tid < 5) bstG[blockIdx.x * 8 + tid] = bstart[tid];
}

// ---- eval: q-tile(16x8) LDS only; banded entries from global ----
__global__ __launch_bounds__(256) void eval_k(
    const float* __restrict__ qp2, const float* __restrict__ kp2,
    const uint32_t* __restrict__ entG, const int* __restrict__ bstG,
    float* __restrict__ lcG) {
  __shared__ float qt[10 * 18 * 32];
  int tid = threadIdx.x;
  int bid = blockIdx.x;
  int b, tin;
  remap1024(bid, b, tin);
  int ty = (tin >> 4) * 8, tx = (tin & 15) * 16;
  const float* qpb = qp2 + (size_t)b * CSTRT * CH;
  const float* kpb = kp2 + (size_t)b * CSTRT * CH;
  load_qtile8(qpb, qt, ty, tx, tid);
  __syncthreads();
  const uint32_t* ent = entG + bid * 1024;
  for (int band = 0; band < 4; band++) {
    int s = bstG[bid * 8 + band], t = bstG[bid * 8 + band + 1];
    for (int i = s + tid; i < t; i += 256) {
      uint32_t en = ent[i];
      int j = en & 7, owner = (en >> 3) & 255;
      int ps = en >> 11;
      float c = cost_full(qt, owner >> 4, owner & 15, kpb, ps >> 8, ps & 255);
      int p = ((ty + (owner >> 4)) << 8) | (tx + (owner & 15));
      lcG[(size_t)(b * NPIX + p) * 8 + j] = c;
    }
    __syncthreads();
  }
}

// ---- init merge: 8-way stable sort per pixel ----
__global__ __launch_bounds__(256) void imerge_k(
    const int* __restrict__ scandG, const float* __restrict__ lcG,
    float* __restrict__ cO, int* __restrict__ sO) {
  int gpix = blockIdx.x * 256 + threadIdx.x;
  int b = gpix >> 16, p = gpix & 0xFFFF;
  int gp8 = gpix * 8;
  float c8[KK];
  int s8[KK];
#pragma unroll
  for (int jj = 0; jj < KK; jj++) {
    c8[jj] = lcG[gp8 + jj];
    s8[jj] = scandG[gp8 + jj];
  }
  // stable odd-even transposition sort (== lax.top_k tie semantics)
#pragma unroll
  for (int ph = 0; ph < KK; ph++) {
#pragma unroll
    for (int i = (ph & 1); i + 1 < KK; i += 2) {
      if (c8[i] > c8[i + 1]) {
        float tc = c8[i]; c8[i] = c8[i + 1]; c8[i + 1] = tc;
        int ts = s8[i]; s8[i] = s8[i + 1]; s8[i + 1] = ts;
      }
    }
  }
  int base = b * KK * NPIX;
#pragma unroll
  for (int jj = 0; jj < KK; jj++) {
    cO[base + jj * NPIX + p] = c8[jj];
    sO[base + jj * NPIX + p] = s8[jj];
  }
}

// ---- iter merge: 14-way stable sort per pixel (dup-copy) ----
__global__ __launch_bounds__(256) void merge_k(
    const float* __restrict__ cI, const int* __restrict__ sI,
    const int* __restrict__ scandG, const int* __restrict__ dupjG,
    const float* __restrict__ lcG,
    float* __restrict__ cO, int* __restrict__ sO) {
  int gpix = blockIdx.x * 256 + threadIdx.x;
  int b = gpix >> 16, p = gpix & 0xFFFF;
  int base = b * KK * NPIX;
  float c14[KK + 6];
  int s14[KK + 6];
#pragma unroll
  for (int jj = 0; jj < KK; jj++) {
    c14[jj] = cI[base + jj * NPIX + p];
    s14[jj] = sI[base + jj * NPIX + p];
  }
  int gp8 = gpix * 8;
#pragma unroll
  for (int j = 0; j < 6; j++) {
    int d = dupjG[gp8 + j];
    c14[KK + j] = (d >= 0) ? c14[d] : lcG[gp8 + j];
    s14[KK + j] = scandG[gp8 + j];
  }
  // stable odd-even transposition sort of 14
#pragma unroll
  for (int ph = 0; ph < 14; ph++) {
#pragma unroll
    for (int i = (ph & 1); i + 1 < 14; i += 2) {
      if (c14[i] > c14[i + 1]) {
        float tc = c14[i]; c14[i] = c14[i + 1]; c14[i + 1] = tc;
        int ts = s14[i]; s14[i] = s14[i + 1]; s14[i + 1] = ts;
      }
    }
  }
#pragma unroll
  for (int jj = 0; jj < KK; jj++) {
    cO[base + jj * NPIX + p] = c14[jj];
    sO[base + jj * NPIX + p] = s14[jj];
  }
}

// ------- attention from transposed vp (px, 64ch), 16-row banded -------
__global__ __launch_bounds__(256) void attn5_k(
    const float* __restrict__ vp, const float* __restrict__ cI,
    const int* __restrict__ sI, float* __restrict__ out) {
  int g = threadIdx.x >> 6;
  int pl = threadIdx.x & 63;
  int gpix = blockIdx.x * 64 + pl;
  int b = gpix >> 16, p = gpix & 0xFFFF;
  int base = b * KK * NPIX;
  float c[KK];
  int off[KK];
#pragma unroll
  for (int j = 0; j < KK; j++) {
    c[j] = cI[base + j * NPIX + p];
    off[j] = sI[base + j * NPIX + p];
  }
  float m = c[0];
  float w[KK];
  float Z = 0.f;
#pragma unroll
  for (int j = 0; j < KK; j++) { w[j] = expf(m - c[j]); Z = Z + w[j]; }
#pragma unroll
  for (int j = 0; j < KK; j++) w[j] = w[j] / Z;
  int bd[KK];
#pragma unroll
  for (int j = 0; j < KK; j++) bd[j] = off[j] >> 12;
  const float* vb = vp + (size_t)b * NPIX * CVN + g * 16;
  float acc[16];
#pragma unroll
  for (int i = 0; i < 16; i++) acc[i] = 0.f;
  for (int band = 0; band < 16; band++) {
#pragma unroll
    for (int j = 0; j < KK; j++) {
      if (bd[j] == band) {
        const float4* vr = (const float4*)(vb + (size_t)off[j] * CVN);
#pragma unroll
        for (int t = 0; t < 4; t++) {
          float4 vv = vr[t];
          acc[t * 4 + 0] = acc[t * 4 + 0] + w[j] * vv.x;
          acc[t * 4 + 1] = acc[t * 4 + 1] + w[j] * vv.y;
          acc[t * 4 + 2] = acc[t * 4 + 2] + w[j] * vv.z;
          acc[t * 4 + 3] = acc[t * 4 + 3] + w[j] * vv.w;
        }
      }
    }
  }
  float* ob = out + (size_t)b * CVN * NPIX;
#pragma unroll
  for (int i = 0; i < 16; i++) ob[(size_t)(g * 16 + i) * NPIX + p] = acc[i];
}

extern "C" void kernel_launch(void* const* d_in, const int* in_sizes, int n_in,
                              void* d_out, int out_size, void* d_ws, size_t ws_size,
                              hipStream_t stream) {
  const float* q = (const float*)d_in[0];
  const float* k = (const float*)d_in[1];
  const float* v = (const float*)d_in[2];
  float* out = (float*)d_out;

  // base key: jax.random.key(42) -> (0,42); split -> enc(base,(0,i))
  uint32_t kA0, kA1, kB0, kB1;
  tf2x32(0u, 42u, 0u, 0u, kA0, kA1);
  tf2x32(0u, 42u, 0u, 1u, kB0, kB1);

  // init keys: fold_in(key,10000/10001) then k2 of split (span=256 -> lower only)
  uint4 ikA, ikB;
  {
    uint32_t f0, f1;
    tf2x32(kA0, kA1, 0u, 10000u, f0, f1); tf2x32(f0, f1, 0u, 1u, ikA.x, ikA.y);
    tf2x32(kA0, kA1, 0u, 10001u, f0, f1); tf2x32(f0, f1, 0u, 1u, ikA.z, ikA.w);
    tf2x32(kB0, kB1, 0u, 10000u, f0, f1); tf2x32(f0, f1, 0u, 1u, ikB.x, ikB.y);
    tf2x32(kB0, kB1, 0u, 10001u, f0, f1); tf2x32(f0, f1, 0u, 1u, ikB.z, ikB.w);
  }

  // ws layout (floats): qp2 | kp2 | cA | cB | sA | sB | vp
  // iter/init scratch aliases vp region; vtr_k runs after iter loop.
  const size_t szPad = (size_t)2 * CSTRT * CH;
  const size_t szCS  = (size_t)2 * KK * NPIX;
  float* qp2 = (float*)d_ws;
  float* kp2 = qp2 + szPad;
  float* cA = kp2 + szPad;
  float* cB = cA + szCS;
  int* sA = (int*)(cB + szCS);
  int* sB = sA + szCS;
  float* vp = (float*)(sB + szCS);

  uint32_t* entG = (uint32_t*)vp;                      // 1024*1024
  int* bstG = (int*)(entG + 1024 * 1024);              // 1024*8
  int* scandG = bstG + 1024 * 8;                       // 2*NPIX*8
  int* dupjG = scandG + (size_t)2 * NPIX * 8;          // 2*NPIX*8
  float* lcG = (float*)(dupjG + (size_t)2 * NPIX * 8); // 2*NPIX*8

  hipMemsetAsync(qp2, 0, szPad * sizeof(float), stream);
  hipMemsetAsync(kp2, 0, szPad * sizeof(float), stream);
  tpad_k<<<2048, 256, 0, stream>>>(q, qp2);
  tpad_k<<<2048, 256, 0, stream>>>(k, kp2);

  // init: gen -> eval -> merge
  igen_k<<<1024, 256, 0, stream>>>(scandG, entG, bstG, ikA, ikB);
  eval_k<<<1024, 256, 0, stream>>>(qp2, kp2, entG, bstG, lcG);
  imerge_k<<<512, 256, 0, stream>>>(scandG, lcG, cA, sA);

  float* ci = cA; int* si = sA;
  float* co = cB; int* so = sB;
  for (int it = 0; it < 5; ++it) {
    // per-iter randint keys: kit=fold_in(key,it); fold_in(kit,2s/2s+1); split
    uint4 ky[2][2], kx[2][2];
    for (int bb = 0; bb < 2; bb++) {
      uint32_t kk0 = bb ? kB0 : kA0, kk1 = bb ? kB1 : kA1;
      uint32_t kit0, kit1;
      tf2x32(kk0, kk1, 0u, (uint32_t)it, kit0, kit1);
      for (int s = 0; s < 2; s++) {
        uint32_t f0, f1, h0, h1, l0, l1;
        tf2x32(kit0, kit1, 0u, (uint32_t)(2 * s), f0, f1);
        tf2x32(f0, f1, 0u, 0u, h0, h1);
        tf2x32(f0, f1, 0u, 1u, l0, l1);
        ky[bb][s] = make_uint4(h0, h1, l0, l1);
        tf2x32(kit0, kit1, 0u, (uint32_t)(2 * s + 1), f0, f1);
        tf2x32(f0, f1, 0u, 0u, h0, h1);
        tf2x32(f0, f1, 0u, 1u, l0, l1);
        kx[bb][s] = make_uint4(h0, h1, l0, l1);
      }
    }
    ggen_k<<<1024, 256, 0, stream>>>(si, scandG, dupjG, entG, bstG,
                                     ky[0][0], kx[0][0], ky[0][1], kx[0][1],
                                     ky[1][0], kx[1][0], ky[1][1], kx[1][1]);
    eval_k<<<1024, 256, 0, stream>>>(qp2, kp2, entG, bstG, lcG);
    merge_k<<<512, 256, 0, stream>>>(ci, si, scandG, dupjG, lcG, co, so);
    float* tc = ci; ci = co; co = tc;
    int* ts = si; si = so; so = ts;
  }

  vtr_k<<<2048, 256, 0, stream>>>(v, vp);
  attn5_k<<<2048, 256, 0, stream>>>(vp, ci, si, out);
}

// Round 22
// 1025.334 us; speedup vs baseline: 1.2079x; 1.2079x over previous
//
#include <hip/hip_runtime.h>
#include <stdint.h>

#define HW 256
#define HWP 258
#define CH 32
#define CVN 64
#define NPIX (HW*HW)
#define KK 8
#define CSTRT (HWP*HWP)

// PRNG (verified r3): partitionable threefry + SPLIT-key randint.
// FINAL (r22 = r19, best measured 1025us): fused 8-band init (16x16 tiles,
//   tap-outer cost) + fused 4-band iter with batch-split XCD remap (each
//   XCD L2 holds one batch's 64-row band ~2.1MB). r21's split/1024-block
//   variant broke band lockstep (FETCH 2x) — occupancy and L2 locality are
//   structurally opposed in this workload; this config is the optimum found.

// ---------------- Threefry-2x32 (JAX-compatible) ----------------
__host__ __device__ __forceinline__ void tf2x32(uint32_t k0, uint32_t k1,
                                                uint32_t x0, uint32_t x1,
                                                uint32_t &o0, uint32_t &o1) {
  const uint32_t ks2 = k0 ^ k1 ^ 0x1BD11BDAu;
  x0 += k0; x1 += k1;
#define TFR(r) x0 += x1; x1 = (x1 << (r)) | (x1 >> (32 - (r))); x1 ^= x0;
  TFR(13) TFR(15) TFR(26) TFR(6)
  x0 += k1;  x1 += ks2 + 1u;
  TFR(17) TFR(29) TFR(16) TFR(24)
  x0 += ks2; x1 += k0 + 2u;
  TFR(13) TFR(15) TFR(26) TFR(6)
  x0 += k0;  x1 += k1 + 3u;
  TFR(17) TFR(29) TFR(16) TFR(24)
  x0 += k1;  x1 += ks2 + 4u;
  TFR(13) TFR(15) TFR(26) TFR(6)
  x0 += ks2; x1 += k0 + 5u;
#undef TFR
  o0 = x0; o1 = x1;
}

__device__ __forceinline__ uint32_t tfbits(uint32_t k0, uint32_t k1, uint32_t idx) {
  uint32_t a, b;
  tf2x32(k0, k1, 0u, idx, a, b);
  return a ^ b;
}

// ------- tiled transpose+pad: (C=32, 65536) -> padded (258,258,32) -------
__global__ __launch_bounds__(256) void tpad_k(const float* __restrict__ src,
                                              float* __restrict__ dst) {
  __shared__ float tile[CH][65];
  int t = blockIdx.x;
  int b = t >> 10;
  int p0 = (t & 1023) * 64;
  int tid = threadIdx.x;
  const float* sb = src + (size_t)b * CH * NPIX;
#pragma unroll
  for (int i = 0; i < 8; i++) {
    int idx = i * 256 + tid;
    int c = idx >> 6, px = idx & 63;
    tile[c][px] = sb[c * NPIX + p0 + px];
  }
  __syncthreads();
  float* db = dst + (size_t)b * CSTRT * CH;
#pragma unroll
  for (int i = 0; i < 8; i++) {
    int idx = i * 256 + tid;
    int px = idx >> 5, c = idx & 31;
    int p = p0 + px;
    int y = p >> 8, x = p & 255;
    db[((size_t)(y + 1) * HWP + (x + 1)) * CH + c] = tile[c][px];
  }
}

// ------- tiled transpose: v (64, 65536) -> vp (65536, 64) -------
__global__ __launch_bounds__(256) void vtr_k(const float* __restrict__ v,
                                             float* __restrict__ vp) {
  __shared__ float tile[CVN][65];
  int t = blockIdx.x;
  int b = t >> 10;
  int p0 = (t & 1023) * 64;
  int tid = threadIdx.x;
  const float* sb = v + (size_t)b * CVN * NPIX;
#pragma unroll
  for (int i = 0; i < 16; i++) {
    int idx = i * 256 + tid;
    int c = idx >> 6, px = idx & 63;
    tile[c][px] = sb[c * NPIX + p0 + px];
  }
  __syncthreads();
  float* db = vp + (size_t)b * NPIX * CVN;
#pragma unroll
  for (int i = 0; i < 16; i++) {
    int idx = i * 256 + tid;
    int px = idx >> 6, c = idx & 63;
    db[(size_t)(p0 + px) * CVN + c] = tile[c][px];
  }
}

// ---- cost A (init, dense): tap-outer FULL unroll; bit-exact ----
__device__ __forceinline__ float cost_full(const float* __restrict__ qt,
                                           int py, int px,
                                           const float* __restrict__ kb2,
                                           int sy, int sx) {
#pragma clang fp contract(off)
  float S[3][3];
  const float* kb = kb2 + ((size_t)sy * HWP + sx) * CH;
#pragma unroll
  for (int dy = 0; dy < 3; dy++) {
#pragma unroll
    for (int dx = 0; dx < 3; dx++) {
      int row = py + dy, col = px + dx;
      const float* qrow = &qt[(row * 18 + col) * 32];
      int rot = 4 * ((row * 3 + col) & 7);
      const float* kr = kb + (dy * HWP + dx) * CH;
      float4 kv[8], qv[8];
#pragma unroll
      for (int i = 0; i < 8; i++) kv[i] = ((const float4*)kr)[i];
#pragma unroll
      for (int i = 0; i < 8; i++)
        qv[i] = *(const float4*)(&qrow[(i * 4 + rot) & 31]);
      float s = 0.f;
#pragma unroll
      for (int i = 0; i < 8; i++) {
        float d;
        d = qv[i].x - kv[i].x; s = s + d * d;
        d = qv[i].y - kv[i].y; s = s + d * d;
        d = qv[i].z - kv[i].z; s = s + d * d;
        d = qv[i].w - kv[i].w; s = s + d * d;
      }
      S[dy][dx] = s;
    }
  }
  float cost = 0.f;
#pragma unroll
  for (int dy = 0; dy < 3; dy++)
#pragma unroll
    for (int dx = 0; dx < 3; dx++) cost = cost + S[dy][dx];
  return cost;
}

// ---- cost B (iter, sparse): ch-outer, 9 accumulators; bit-exact ----
__device__ __forceinline__ float cost_ch(const float* __restrict__ qt,
                                         int py, int px,
                                         const float* __restrict__ kb2,
                                         int sy, int sx) {
#pragma clang fp contract(off)
  float S[3][3];
#pragma unroll
  for (int dy = 0; dy < 3; dy++)
#pragma unroll
    for (int dx = 0; dx < 3; dx++) S[dy][dx] = 0.f;
  const float* kb = kb2 + ((size_t)sy * HWP + sx) * CH;
#pragma unroll 2
  for (int ch = 0; ch < CH; ch += 4) {
#pragma unroll
    for (int dy = 0; dy < 3; dy++) {
#pragma unroll
      for (int dx = 0; dx < 3; dx++) {
        int row = py + dy, col = px + dx;
        const float4 qv = *(const float4*)(&qt[(row * 18 + col) * 32 +
                                              ((ch + 4 * ((row * 3 + col) & 7)) & 31)]);
        const float4 kv = *(const float4*)(kb + (dy * HWP + dx) * CH + ch);
        float d;
        d = qv.x - kv.x; S[dy][dx] = S[dy][dx] + d * d;
        d = qv.y - kv.y; S[dy][dx] = S[dy][dx] + d * d;
        d = qv.z - kv.z; S[dy][dx] = S[dy][dx] + d * d;
        d = qv.w - kv.w; S[dy][dx] = S[dy][dx] + d * d;
      }
    }
  }
  float cost = 0.f;
#pragma unroll
  for (int dy = 0; dy < 3; dy++)
#pragma unroll
    for (int dx = 0; dx < 3; dx++) cost = cost + S[dy][dx];
  return cost;
}

// load q tile: padded rows ty..ty+17, cols tx..tx+17, rot-swizzled
__device__ __forceinline__ void load_qtile16(const float* __restrict__ qpb,
                                             float* __restrict__ qt,
                                             int ty, int tx, int tid) {
  for (int i = tid; i < 18 * 18 * 8; i += 256) {
    int c4 = i & 7;
    int col = (i >> 3) % 18;
    int row = (i >> 3) / 18;
    float4 v = *(const float4*)(qpb + ((size_t)(ty + row) * HWP + (tx + col)) * CH + c4 * 4);
    *(float4*)(&qt[(row * 18 + col) * 32 +
                   ((c4 * 4 + 4 * ((row * 3 + col) & 7)) & 31)]) = v;
  }
}

// ---------------- init: 16x16 tile, 8 cand/thread, 8 bands ----------
__global__ __launch_bounds__(256) void init11_k(
    const float* __restrict__ qp2, const float* __restrict__ kp2,
    float* __restrict__ cO, int* __restrict__ sO,
    uint4 ikA, uint4 ikB) {
  __shared__ float qt[18 * 18 * 32];
  __shared__ uint32_t ent[2048];
  __shared__ float lc[256][9];
  __shared__ int bcnt[8], bstart[9], boff[8];
  int tid = threadIdx.x;
  int grp = blockIdx.x;            // 0..511
  int b = grp >> 8;
  int tin = grp & 255;
  int ty = (tin >> 4) * 16, tx = (tin & 15) * 16;
  const float* qpb = qp2 + (size_t)b * CSTRT * CH;
  const float* kpb = kp2 + (size_t)b * CSTRT * CH;
  load_qtile16(qpb, qt, ty, tx, tid);
  if (tid < 8) bcnt[tid] = 0;
  __syncthreads();

  int py = tid >> 4, px = tid & 15;
  int p = ((ty + py) << 8) | (tx + px);
  uint4 K = b ? ikB : ikA;
  int scand[KK];
#pragma unroll
  for (int j = 0; j < KK; j++) {
    uint32_t cand = (uint32_t)(j * NPIX + p);
    int sy = (int)(tfbits(K.x, K.y, cand) & 255u);
    int sx = (int)(tfbits(K.z, K.w, cand) & 255u);
    scand[j] = (sy << 8) | sx;
    atomicAdd(&bcnt[sy >> 5], 1);
  }
  __syncthreads();
  if (tid == 0) {
    int s = 0;
#pragma unroll
    for (int i = 0; i < 8; i++) { bstart[i] = s; boff[i] = s; s += bcnt[i]; }
    bstart[8] = s;
  }
  __syncthreads();
#pragma unroll
  for (int j = 0; j < KK; j++) {
    int pos = atomicAdd(&boff[scand[j] >> 13], 1);
    ent[pos] = ((uint32_t)scand[j] << 11) | ((uint32_t)tid << 3) | (uint32_t)j;
  }
  __syncthreads();

  for (int band = 0; band < 8; band++) {
    int s = bstart[band], t = bstart[band + 1];
    for (int i = s + tid; i < t; i += 256) {
      uint32_t en = ent[i];
      int j = en & 7, owner = (en >> 3) & 255;
      int ps = en >> 11;
      lc[owner][j] = cost_full(qt, owner >> 4, owner & 15, kpb, ps >> 8, ps & 255);
    }
    __syncthreads();
  }

  float c8[KK];
  int s8[KK];
#pragma unroll
  for (int jj = 0; jj < KK; jj++) { c8[jj] = lc[tid][jj]; s8[jj] = scand[jj]; }
  // stable odd-even transposition sort (== lax.top_k tie semantics)
#pragma unroll
  for (int ph = 0; ph < KK; ph++) {
#pragma unroll
    for (int i = (ph & 1); i + 1 < KK; i += 2) {
      if (c8[i] > c8[i + 1]) {
        float tc = c8[i]; c8[i] = c8[i + 1]; c8[i + 1] = tc;
        int ts = s8[i]; s8[i] = s8[i + 1]; s8[i + 1] = ts;
      }
    }
  }
  int base = b * KK * NPIX;
#pragma unroll
  for (int jj = 0; jj < KK; jj++) {
    cO[base + jj * NPIX + p] = c8[jj];
    sO[base + jj * NPIX + p] = s8[jj];
  }
}

// ---------------- prop candidate helper (r3-verified) ----------------
__device__ __forceinline__ void prop_cand(const int* __restrict__ sI, int base,
                                          int y, int x, int c, int &nsy, int &nsx) {
  int np;
  if (c == 0)      np = (y << 8) | ((x + HW - 1) & (HW - 1));
  else if (c == 1) np = (y << 8) | ((x + 1) & (HW - 1));
  else if (c == 2) np = (((y + HW - 1) & (HW - 1)) << 8) | x;
  else             np = (((y + 1) & (HW - 1)) << 8) | x;
  int sv = sI[base + np];
  if (c == 0)      { nsy = sv >> 8;       nsx = (sv & 255) + 1; }
  else if (c == 1) { nsy = sv >> 8;       nsx = (sv & 255) - 1; }
  else if (c == 2) { nsy = (sv >> 8) + 1; nsx = sv & 255; }
  else             { nsy = (sv >> 8) - 1; nsx = sv & 255; }
}

__device__ __forceinline__ int rand_off(uint4 K, uint32_t p, int s) {
  uint32_t hi = tfbits(K.x, K.y, p), lo = tfbits(K.z, K.w, p);
  return (s == 0) ? (int)(((hi % 257u) + (lo % 257u)) % 257u) - 128
                  : (int)((((hi % 129u) * 16u) + (lo % 129u)) % 129u) - 64;
}

// -- iter: 16x16 tile, dedup, 4 bands of 64 rows, batch-split XCD remap --
__global__ __launch_bounds__(256) void iter13_k(
    const float* __restrict__ qp2, const float* __restrict__ kp2,
    const float* __restrict__ cI, const int* __restrict__ sI,
    float* __restrict__ cO, int* __restrict__ sO,
    uint4 A0y, uint4 A0x, uint4 A1y, uint4 A1x,
    uint4 B0y, uint4 B0x, uint4 B1y, uint4 B1x) {
  __shared__ float qt[18 * 18 * 32];
  __shared__ uint32_t ent[1536];
  __shared__ float lc[256][7];
  __shared__ int bcnt[4], bstart[5], boff[4];
  int tid = threadIdx.x;
  int bid = blockIdx.x;
  // batch-split: XCD (bid%8) 0-3 -> batch 0, 4-7 -> batch 1; tin bijective
  int b = ((bid & 7) >= 4) ? 1 : 0;
  int tin = ((bid >> 3) << 2) | (bid & 3);
  int ty = (tin >> 4) * 16, tx = (tin & 15) * 16;
  int base = b * KK * NPIX;
  const float* qpb = qp2 + (size_t)b * CSTRT * CH;
  const float* kpb = kp2 + (size_t)b * CSTRT * CH;
  load_qtile16(qpb, qt, ty, tx, tid);
  if (tid < 4) bcnt[tid] = 0;
  __syncthreads();

  int py = tid >> 4, px = tid & 15;
  int y = ty + py, x = tx + px;
  int p = (y << 8) | x;
  int pcur[KK];
#pragma unroll
  for (int jj = 0; jj < KK; jj++) pcur[jj] = sI[base + jj * NPIX + p];

  int scand[6];
  int dupj[6];
#pragma unroll
  for (int j = 0; j < 6; j++) {
    int nsy, nsx;
    if (j < 4) {
      prop_cand(sI, base, y, x, j, nsy, nsx);
    } else {
      int by = pcur[0] >> 8, bx = pcur[0] & 255;
      int s = j - 4;
      uint4 KY = b ? (s ? B1y : B0y) : (s ? A1y : A0y);
      uint4 KX = b ? (s ? B1x : B0x) : (s ? A1x : A0x);
      nsy = by + rand_off(KY, (uint32_t)p, s);
      nsx = bx + rand_off(KX, (uint32_t)p, s);
    }
    nsy = min(max(nsy, 0), HW - 1);
    nsx = min(max(nsx, 0), HW - 1);
    int ps = (nsy << 8) | nsx;
    scand[j] = ps;
    int d = -1;
#pragma unroll
    for (int jj = 0; jj < KK; jj++)
      if (d < 0 && pcur[jj] == ps) d = jj;
    dupj[j] = d;
    if (d < 0) atomicAdd(&bcnt[nsy >> 6], 1);
  }
  __syncthreads();
  if (tid == 0) {
    int s = 0;
#pragma unroll
    for (int i = 0; i < 4; i++) { bstart[i] = s; boff[i] = s; s += bcnt[i]; }
    bstart[4] = s;
  }
  __syncthreads();
#pragma unroll
  for (int j = 0; j < 6; j++) {
    if (dupj[j] < 0) {
      int pos = atomicAdd(&boff[scand[j] >> 14], 1);
      ent[pos] = ((uint32_t)scand[j] << 11) | ((uint32_t)tid << 3) | (uint32_t)j;
    }
  }
  __syncthreads();

  for (int band = 0; band < 4; band++) {
    int s = bstart[band], t = bstart[band + 1];
    for (int i = s + tid; i < t; i += 256) {
      uint32_t en = ent[i];
      int j = en & 7, owner = (en >> 3) & 255;
      int ps = en >> 11;
      lc[owner][j] = cost_ch(qt, owner >> 4, owner & 15, kpb, ps >> 8, ps & 255);
    }
    __syncthreads();
  }

  float c14[KK + 6];
  int s14[KK + 6];
#pragma unroll
  for (int jj = 0; jj < KK; jj++) {
    c14[jj] = cI[base + jj * NPIX + p];
    s14[jj] = pcur[jj];
  }
#pragma unroll
  for (int j = 0; j < 6; j++) {
    int d = dupj[j];
    c14[KK + j] = (d >= 0) ? c14[d] : lc[tid][j];
    s14[KK + j] = scand[j];
  }
  // stable odd-even transposition sort of 14
#pragma unroll
  for (int ph = 0; ph < 14; ph++) {
#pragma unroll
    for (int i = (ph & 1); i + 1 < 14; i += 2) {
      if (c14[i] > c14[i + 1]) {
        float tc = c14[i]; c14[i] = c14[i + 1]; c14[i + 1] = tc;
        int ts = s14[i]; s14[i] = s14[i + 1]; s14[i + 1] = ts;
      }
    }
  }
#pragma unroll
  for (int jj = 0; jj < KK; jj++) {
    cO[base + jj * NPIX + p] = c14[jj];
    sO[base + jj * NPIX + p] = s14[jj];
  }
}

// ------- attention from transposed vp (px, 64ch), 16-row banded -------
__global__ __launch_bounds__(256) void attn5_k(
    const float* __restrict__ vp, const float* __restrict__ cI,
    const int* __restrict__ sI, float* __restrict__ out) {
  int g = threadIdx.x >> 6;
  int pl = threadIdx.x & 63;
  int gpix = blockIdx.x * 64 + pl;
  int b = gpix >> 16, p = gpix & 0xFFFF;
  int base = b * KK * NPIX;
  float c[KK];
  int off[KK];
#pragma unroll
  for (int j = 0; j < KK; j++) {
    c[j] = cI[base + j * NPIX + p];
    off[j] = sI[base + j * NPIX + p];
  }
  float m = c[0];
  float w[KK];
  float Z = 0.f;
#pragma unroll
  for (int j = 0; j < KK; j++) { w[j] = expf(m - c[j]); Z = Z + w[j]; }
#pragma unroll
  for (int j = 0; j < KK; j++) w[j] = w[j] / Z;
  int bd[KK];
#pragma unroll
  for (int j = 0; j < KK; j++) bd[j] = off[j] >> 12;
  const float* vb = vp + (size_t)b * NPIX * CVN + g * 16;
  float acc[16];
#pragma unroll
  for (int i = 0; i < 16; i++) acc[i] = 0.f;
  for (int band = 0; band < 16; band++) {
#pragma unroll
    for (int j = 0; j < KK; j++) {
      if (bd[j] == band) {
        const float4* vr = (const float4*)(vb + (size_t)off[j] * CVN);
#pragma unroll
        for (int t = 0; t < 4; t++) {
          float4 vv = vr[t];
          acc[t * 4 + 0] = acc[t * 4 + 0] + w[j] * vv.x;
          acc[t * 4 + 1] = acc[t * 4 + 1] + w[j] * vv.y;
          acc[t * 4 + 2] = acc[t * 4 + 2] + w[j] * vv.z;
          acc[t * 4 + 3] = acc[t * 4 + 3] + w[j] * vv.w;
        }
      }
    }
  }
  float* ob = out + (size_t)b * CVN * NPIX;
#pragma unroll
  for (int i = 0; i < 16; i++) ob[(size_t)(g * 16 + i) * NPIX + p] = acc[i];
}

extern "C" void kernel_launch(void* const* d_in, const int* in_sizes, int n_in,
                              void* d_out, int out_size, void* d_ws, size_t ws_size,
                              hipStream_t stream) {
  const float* q = (const float*)d_in[0];
  const float* k = (const float*)d_in[1];
  const float* v = (const float*)d_in[2];
  float* out = (float*)d_out;

  // base key: jax.random.key(42) -> (0,42); split -> enc(base,(0,i))
  uint32_t kA0, kA1, kB0, kB1;
  tf2x32(0u, 42u, 0u, 0u, kA0, kA1);
  tf2x32(0u, 42u, 0u, 1u, kB0, kB1);

  // init keys: fold_in(key,10000/10001) then k2 of split (span=256 -> lower only)
  uint4 ikA, ikB;
  {
    uint32_t f0, f1;
    tf2x32(kA0, kA1, 0u, 10000u, f0, f1); tf2x32(f0, f1, 0u, 1u, ikA.x, ikA.y);
    tf2x32(kA0, kA1, 0u, 10001u, f0, f1); tf2x32(f0, f1, 0u, 1u, ikA.z, ikA.w);
    tf2x32(kB0, kB1, 0u, 10000u, f0, f1); tf2x32(f0, f1, 0u, 1u, ikB.x, ikB.y);
    tf2x32(kB0, kB1, 0u, 10001u, f0, f1); tf2x32(f0, f1, 0u, 1u, ikB.z, ikB.w);
  }

  // ws layout (floats): qp2 | kp2 | cA | cB | sA | sB | vp
  const size_t szPad = (size_t)2 * CSTRT * CH;
  const size_t szCS  = (size_t)2 * KK * NPIX;
  float* qp2 = (float*)d_ws;
  float* kp2 = qp2 + szPad;
  float* cA = kp2 + szPad;
  float* cB = cA + szCS;
  int* sA = (int*)(cB + szCS);
  int* sB = sA + szCS;
  float* vp = (float*)(sB + szCS);

  hipMemsetAsync(qp2, 0, szPad * sizeof(float), stream);
  hipMemsetAsync(kp2, 0, szPad * sizeof(float), stream);
  tpad_k<<<2048, 256, 0, stream>>>(q, qp2);
  tpad_k<<<2048, 256, 0, stream>>>(k, kp2);
  vtr_k<<<2048, 256, 0, stream>>>(v, vp);

  init11_k<<<512, 256, 0, stream>>>(qp2, kp2, cA, sA, ikA, ikB);

  float* ci = cA; int* si = sA;
  float* co = cB; int* so = sB;
  for (int it = 0; it < 5; ++it) {
    // per-iter randint keys: kit=fold_in(key,it); fold_in(kit,2s/2s+1); split
    uint4 ky[2][2], kx[2][2];
    for (int bb = 0; bb < 2; bb++) {
      uint32_t kk0 = bb ? kB0 : kA0, kk1 = bb ? kB1 : kA1;
      uint32_t kit0, kit1;
      tf2x32(kk0, kk1, 0u, (uint32_t)it, kit0, kit1);
      for (int s = 0; s < 2; s++) {
        uint32_t f0, f1, h0, h1, l0, l1;
        tf2x32(kit0, kit1, 0u, (uint32_t)(2 * s), f0, f1);
        tf2x32(f0, f1, 0u, 0u, h0, h1);
        tf2x32(f0, f1, 0u, 1u, l0, l1);
        ky[bb][s] = make_uint4(h0, h1, l0, l1);
        tf2x32(kit0, kit1, 0u, (uint32_t)(2 * s + 1), f0, f1);
        tf2x32(f0, f1, 0u, 0u, h0, h1);
        tf2x32(f0, f1, 0u, 1u, l0, l1);
        kx[bb][s] = make_uint4(h0, h1, l0, l1);
      }
    }
    iter13_k<<<512, 256, 0, stream>>>(qp2, kp2, ci, si, co, so,
                                      ky[0][0], kx[0][0], ky[0][1], kx[0][1],
                                      ky[1][0], kx[1][0], ky[1][1], kx[1][1]);
    float* tc = ci; ci = co; co = tc;
    int* ts = si; si = so; so = ts;
  }
  attn5_k<<<2048, 256, 0, stream>>>(vp, ci, si, out);
}